// Round 3
// baseline (1797.509 us; speedup 1.0000x reference)
//
#include <hip/hip_runtime.h>
#include <cstdint>

#define BT 4096
#define HD 2048
#define VD 32000

typedef __attribute__((ext_vector_type(4))) float float4_t;
typedef __attribute__((ext_vector_type(4))) short short4_t;
typedef __attribute__((ext_vector_type(8))) short short8_t;
typedef __attribute__((ext_vector_type(8))) unsigned short ushort8_t;

constexpr int BM = 128, BN = 128, BK = 32;

// f32 -> bf16 round-to-nearest-even (inputs are normal, no NaN handling needed)
__device__ __forceinline__ unsigned short f2bf(float f) {
  unsigned u = __float_as_uint(f);
  u += 0x7FFFu + ((u >> 16) & 1u);
  return (unsigned short)(u >> 16);
}

__device__ __forceinline__ float bf2f(unsigned short h) {
  return __uint_as_float((unsigned)h << 16);
}

__device__ __forceinline__ short8_t pack8(float4_t a, float4_t b) {
  short8_t h;
  h[0] = (short)f2bf(a.x); h[1] = (short)f2bf(a.y);
  h[2] = (short)f2bf(a.z); h[3] = (short)f2bf(a.w);
  h[4] = (short)f2bf(b.x); h[5] = (short)f2bf(b.y);
  h[6] = (short)f2bf(b.z); h[7] = (short)f2bf(b.w);
  return h;
}

// async global->LDS, 16B per lane; LDS dest is wave-uniform base + lane*16.
__device__ __forceinline__ void async_copy16(const void* g, void* l) {
  __builtin_amdgcn_global_load_lds(
      (__attribute__((address_space(1))) void*)(uintptr_t)(g),
      (__attribute__((address_space(3))) void*)(uint32_t)(uintptr_t)(l),
      16, 0, 0);
}

// One kernel for all four f32->bf16 casts (fewer launch gaps).
__global__ __launch_bounds__(256) void cast4_f32_to_bf16(
    const float4_t* __restrict__ s0, short4_t* __restrict__ d0,
    const float4_t* __restrict__ s1, short4_t* __restrict__ d1,
    const float4_t* __restrict__ s2, short4_t* __restrict__ d2,
    const float4_t* __restrict__ s3, short4_t* __restrict__ d3) {
  const long XN4 = (long)BT * HD / 4;
  const long WN4 = (long)VD * HD / 4;
  const long total = 2 * XN4 + 2 * WN4;
  for (long i = blockIdx.x * 256L + threadIdx.x; i < total; i += gridDim.x * 256L) {
    const float4_t* s; short4_t* d; long j = i;
    if (j < XN4) { s = s0; d = d0; }
    else if ((j -= XN4) < XN4) { s = s1; d = d1; }
    else if ((j -= XN4) < WN4) { s = s2; d = d2; }
    else { j -= WN4; s = s3; d = d3; }
    float4_t v = s[j];
    short4_t o;
    o.x = (short)f2bf(v.x); o.y = (short)f2bf(v.y);
    o.z = (short)f2bf(v.z); o.w = (short)f2bf(v.w);
    d[j] = o;
  }
}

// legacy swizzle for 128x128 fallback kernels
__device__ __forceinline__ int swz(int row) { return (row ^ (row >> 2)) & 3; }

// ---------------------------------------------------------------------------
// Legacy 128x128 tile (used by fallback ws paths) — unchanged, verified.
// ---------------------------------------------------------------------------
template <bool F32SRC>
__device__ __forceinline__ void ktile(const void* A, const void* B,
                                      float4_t (&acc)[4][4],
                                      unsigned short* As, unsigned short* Bs,
                                      int m0, int n0) {
  const int tid = threadIdx.x;
  const int lane = tid & 63;
  const int wave = tid >> 6;
  const int wm = wave >> 1, wn = wave & 1;
  const int r0 = tid >> 2, c0 = tid & 3;
  const int cg = c0 ^ swz(r0);
  const int row16 = lane & 15, kq = lane >> 4;
  const int kqs = kq ^ swz(row16);
  const int aoff = (wm * 64 + row16) * BK + kqs * 8;
  const int boff = (wn * 64 + row16) * BK + kqs * 8;
  const int lds0 = __builtin_amdgcn_readfirstlane(wave * 1024);
  const int lds1 = __builtin_amdgcn_readfirstlane(4096 + wave * 1024);

  const unsigned short* Ab = nullptr; const unsigned short* Bb = nullptr;
  const float* Af = nullptr; const float* Bf = nullptr;
  if constexpr (!F32SRC) {
    Ab = (const unsigned short*)A + (size_t)(m0 + r0) * HD + cg * 8;
    Bb = (const unsigned short*)B + (size_t)(n0 + r0) * HD + cg * 8;
  } else {
    Af = (const float*)A + (size_t)(m0 + r0) * HD + cg * 8;
    Bf = (const float*)B + (size_t)(n0 + r0) * HD + cg * 8;
  }

  for (int kb = 0; kb < HD / BK; ++kb) {
    const int ke = kb * BK;
    if constexpr (!F32SRC) {
      async_copy16(Ab + ke, (char*)As + lds0);
      async_copy16(Ab + (size_t)64 * HD + ke, (char*)As + lds1);
      async_copy16(Bb + ke, (char*)Bs + lds0);
      async_copy16(Bb + (size_t)64 * HD + ke, (char*)Bs + lds1);
    } else {
      short8_t hA0 = pack8(*(const float4_t*)(Af + ke), *(const float4_t*)(Af + ke + 4));
      short8_t hA1 = pack8(*(const float4_t*)(Af + (size_t)64 * HD + ke),
                           *(const float4_t*)(Af + (size_t)64 * HD + ke + 4));
      short8_t hB0 = pack8(*(const float4_t*)(Bf + ke), *(const float4_t*)(Bf + ke + 4));
      short8_t hB1 = pack8(*(const float4_t*)(Bf + (size_t)64 * HD + ke),
                           *(const float4_t*)(Bf + (size_t)64 * HD + ke + 4));
      *(short8_t*)((char*)As + tid * 16) = hA0;
      *(short8_t*)((char*)As + 4096 + tid * 16) = hA1;
      *(short8_t*)((char*)Bs + tid * 16) = hB0;
      *(short8_t*)((char*)Bs + 4096 + tid * 16) = hB1;
    }
    __syncthreads();
    short8_t af[4], bfv[4];
#pragma unroll
    for (int mi = 0; mi < 4; ++mi) af[mi] = *(const short8_t*)(As + aoff + mi * 16 * BK);
#pragma unroll
    for (int ni = 0; ni < 4; ++ni) bfv[ni] = *(const short8_t*)(Bs + boff + ni * 16 * BK);
#pragma unroll
    for (int mi = 0; mi < 4; ++mi)
#pragma unroll
      for (int ni = 0; ni < 4; ++ni)
        acc[mi][ni] = __builtin_amdgcn_mfma_f32_16x16x32_bf16(af[mi], bfv[ni], acc[mi][ni], 0, 0, 0);
    __syncthreads();
  }
}

// Pass 1 legacy (fallback paths): 128x128 tile.
template <bool F32SRC, bool STORE>
__global__ __launch_bounds__(256, 2) void gemm_pass1(
    const void* A0, const void* A1, const void* B0, const void* B1,
    float* __restrict__ rowsum, unsigned short* __restrict__ store) {
  __shared__ __align__(16) unsigned short As[BM * BK];
  __shared__ __align__(16) unsigned short Bs[BN * BK];
  const int m0 = blockIdx.x * BM;
  const int n0 = blockIdx.y * BN;
  const int z = blockIdx.z;
  const void* A = z ? A1 : A0;
  const void* B = z ? B1 : B0;
  float4_t acc[4][4] = {};
  ktile<F32SRC>(A, B, acc, As, Bs, m0, n0);

  const int tid = threadIdx.x;
  const int lane = tid & 63;
  const int wave = tid >> 6;
  const int wm = wave >> 1, wn = wave & 1;
  const int row16 = lane & 15, kq = lane >> 4;

  if constexpr (STORE) {
    unsigned short* st = store + (size_t)z * BT * VD;
#pragma unroll
    for (int mi = 0; mi < 4; ++mi)
#pragma unroll
      for (int r = 0; r < 4; ++r) {
        const size_t grow = (size_t)(m0 + wm * 64 + mi * 16 + kq * 4 + r);
        const size_t gc0 = (size_t)(n0 + wn * 64 + row16);
#pragma unroll
        for (int ni = 0; ni < 4; ++ni)
          st[grow * VD + gc0 + ni * 16] = f2bf(acc[mi][ni][r]);
      }
  }

  float* rs = rowsum + z * BT;
#pragma unroll
  for (int mi = 0; mi < 4; ++mi)
#pragma unroll
    for (int r = 0; r < 4; ++r) {
      float s = __expf(acc[mi][0][r]) + __expf(acc[mi][1][r]) +
                __expf(acc[mi][2][r]) + __expf(acc[mi][3][r]);
      s += __shfl_xor(s, 1);
      s += __shfl_xor(s, 2);
      s += __shfl_xor(s, 4);
      s += __shfl_xor(s, 8);
      if (row16 == 0) atomicAdd(&rs[m0 + wm * 64 + mi * 16 + kq * 4 + r], s);
    }
}

// ---------------------------------------------------------------------------
// 256x256 deep-pipelined GEMM, v3: within-wave frag double-buffering.
//  - M-packed LDS [128 rows][128B], chunk c stores logical c^(R&7): verified
//    conflict-free (round 2: SQ_LDS_BANK_CONFLICT = 0).
//  - Ring of 4 slots, stage depth 2 (STAGE(kt+2) at top of kt), uniform
//    vmcnt(4) + ONE barrier per kt. At the barrier of body kt, tile kt+1 is
//    globally resident, so body kt reads tile kt+1's a0/b frags WHILE doing
//    tile kt's 32 MFMA -> LDS-read traffic hides under the matrix pipe.
//  - a1 (second m-half of A) is read at body start for the CURRENT tile;
//    its latency hides under MFMA half0 (in-order lgkm completion).
//  - WAR: reads of tile kt-2 are lgkm-drained before MFMA(kt-2), one full
//    barrier before STAGE(kt+2) overwrites that slot.
//  - Tail: clamped re-stage of tile 63 keeps counts uniform (identical-data
//    rewrite, benign); kt=63 peeled without next-reads.
// ---------------------------------------------------------------------------
constexpr int BK2 = 32;

__global__ __launch_bounds__(512, 2) void gemm256_pass1(
    const unsigned short* __restrict__ bXs, const unsigned short* __restrict__ bXt,
    const unsigned short* __restrict__ bWs, const unsigned short* __restrict__ bWt,
    float* __restrict__ rowsum, unsigned short* __restrict__ store) {
  __shared__ __align__(16) unsigned short lds[4 * 16384];  // 128 KiB

  const int z = blockIdx.y;
  const unsigned short* A = z ? bXt : bXs;
  const unsigned short* B = z ? bWt : bWs;

  // bijective XCD swizzle: 2000 wg/z, 2000 % 8 == 0, 250 per XCD.
  const int o = blockIdx.x;
  const int s = (o & 7) * 250 + (o >> 3);
  const int m0 = (s & 15) * 256;   // m fastest: consecutive s share the W-panel
  const int n0 = (s >> 4) * 256;

  const int tid = threadIdx.x;
  const int lane = tid & 63;
  const int wave = tid >> 6;
  const int wm = wave >> 2;   // 0..1
  const int wn = wave & 3;    // 0..3
  const int row16 = lane & 15, kq = lane >> 4;
  const int rh = row16 >> 1;                       // 3-bit swizzle key (R&7)
  const int cA = (((row16 & 1) << 2) | kq) ^ rh;   // swizzled 16B chunk 0..7

  // Staging source map (inverse-swizzled global addresses; LDS dest linear).
  const int lr = lane >> 3, lc = lane & 7;
  const int cl = lc ^ lr;
  const int k8 = (cl & 3) * 8;
  const int mloc0 = (wave * 2 + 0) * 16 + 2 * lr + (cl >> 2);
  const int mloc1 = (wave * 2 + 1) * 16 + 2 * lr + (cl >> 2);
  const unsigned short* srcA0 = A + (size_t)(m0 + mloc0) * HD + k8;
  const unsigned short* srcA1 = A + (size_t)(m0 + mloc1) * HD + k8;
  const unsigned short* srcB0 = B + (size_t)(n0 + mloc0) * HD + k8;
  const unsigned short* srcB1 = B + (size_t)(n0 + mloc1) * HD + k8;
  const int stA0 = __builtin_amdgcn_readfirstlane((wave * 2 + 0) * 1024);
  const int stA1 = __builtin_amdgcn_readfirstlane((wave * 2 + 1) * 1024);

#define STAGE(ktv, slot)                                                 \
  do {                                                                   \
    char* _sb = (char*)lds + (slot) * 32768;                             \
    async_copy16(srcA0 + (size_t)(ktv) * BK2, _sb + stA0);               \
    async_copy16(srcA1 + (size_t)(ktv) * BK2, _sb + stA1);               \
    async_copy16(srcB0 + (size_t)(ktv) * BK2, _sb + 16384 + stA0);       \
    async_copy16(srcB1 + (size_t)(ktv) * BK2, _sb + 16384 + stA1);       \
  } while (0)

  float4_t acc[8][4] = {};
  const int aoffE = (wm * 64 + rh) * 64 + cA * 8;
  const int boffE = (wn * 32 + rh) * 64 + cA * 8;

  short8_t a0A[4], bA[4], a0B[4], bB[4], a1[4];

  // Prologue: stage tiles 0,1; confirm tile 0; read its a0/b frags.
  STAGE(0, 0);
  STAGE(1, 1);
  asm volatile("s_waitcnt vmcnt(4)" ::: "memory");
  __builtin_amdgcn_s_barrier();
  {
    const unsigned short* As0 = lds;
    const unsigned short* Bs0 = lds + 8192;
#pragma unroll
    for (int mi = 0; mi < 4; ++mi) a0A[mi] = *(const short8_t*)(As0 + aoffE + mi * 512);
#pragma unroll
    for (int ni = 0; ni < 4; ++ni) bA[ni] = *(const short8_t*)(Bs0 + boffE + ni * 512);
  }

#define KBODY(KT, CA, CB, NA, NB, DO_NEXT)                                    \
  do {                                                                        \
    const int _ktS = ((KT) + 2 > 63) ? 63 : (KT) + 2;                         \
    STAGE(_ktS, _ktS & 3);                                                    \
    asm volatile("s_waitcnt vmcnt(4)" ::: "memory");                          \
    __builtin_amdgcn_s_barrier();                                             \
    const unsigned short* _As = lds + ((KT) & 3) * 16384;                     \
    _Pragma("unroll")                                                         \
    for (int mi = 0; mi < 4; ++mi)                                            \
      a1[mi] = *(const short8_t*)(_As + aoffE + (4 + mi) * 512);              \
    if (DO_NEXT) {                                                            \
      const unsigned short* _An = lds + (((KT) + 1) & 3) * 16384;             \
      const unsigned short* _Bn = _An + 8192;                                 \
      _Pragma("unroll")                                                       \
      for (int mi = 0; mi < 4; ++mi)                                          \
        NA[mi] = *(const short8_t*)(_An + aoffE + mi * 512);                  \
      _Pragma("unroll")                                                       \
      for (int ni = 0; ni < 4; ++ni)                                          \
        NB[ni] = *(const short8_t*)(_Bn + boffE + ni * 512);                  \
    }                                                                         \
    __builtin_amdgcn_s_setprio(1);                                            \
    _Pragma("unroll")                                                         \
    for (int mi = 0; mi < 4; ++mi)                                            \
      _Pragma("unroll")                                                       \
      for (int ni = 0; ni < 4; ++ni)                                          \
        acc[mi][ni] = __builtin_amdgcn_mfma_f32_16x16x32_bf16(                \
            CA[mi], CB[ni], acc[mi][ni], 0, 0, 0);                            \
    _Pragma("unroll")                                                         \
    for (int mi = 0; mi < 4; ++mi)                                            \
      _Pragma("unroll")                                                       \
      for (int ni = 0; ni < 4; ++ni)                                          \
        acc[4 + mi][ni] = __builtin_amdgcn_mfma_f32_16x16x32_bf16(            \
            a1[mi], CB[ni], acc[4 + mi][ni], 0, 0, 0);                        \
    __builtin_amdgcn_s_setprio(0);                                            \
  } while (0)

#pragma unroll 1
  for (int kt = 0; kt < 62; kt += 2) {
    KBODY(kt,     a0A, bA, a0B, bB, 1);
    KBODY(kt + 1, a0B, bB, a0A, bA, 1);
  }
  KBODY(62, a0A, bA, a0B, bB, 1);
  KBODY(63, a0B, bB, a0A, bA, 0);
#undef KBODY
#undef STAGE

  // drain remaining async LDS writes before the wave can exit.
  asm volatile("s_waitcnt vmcnt(0)" ::: "memory");

  // Epilogue: store bf16 logits + per-row sum(exp).
  unsigned short* st = store + (size_t)z * BT * VD;
  float* rs = rowsum + z * BT;
#pragma unroll
  for (int mi = 0; mi < 8; ++mi)
#pragma unroll
    for (int r = 0; r < 4; ++r) {
      const size_t grow = (size_t)(m0 + wm * 128 + mi * 16 + kq * 4 + r);
      const size_t gc0 = (size_t)(n0 + wn * 64 + row16);
#pragma unroll
      for (int ni = 0; ni < 4; ++ni)
        st[grow * VD + gc0 + ni * 16] = f2bf(acc[mi][ni][r]);
      float ssum = __expf(acc[mi][0][r]) + __expf(acc[mi][1][r]) +
                   __expf(acc[mi][2][r]) + __expf(acc[mi][3][r]);
      ssum += __shfl_xor(ssum, 1);
      ssum += __shfl_xor(ssum, 2);
      ssum += __shfl_xor(ssum, 4);
      ssum += __shfl_xor(ssum, 8);
      if (row16 == 0) atomicAdd(&rs[grow], ssum);
    }
}

// stats[i] = log(sum_exp) -> LSE; thread 0 seeds out with +ln2 (plain store,
// ordered before pass-2 atomics on the same stream).
__global__ __launch_bounds__(256) void lse_fix(float* __restrict__ stats,
                                               float* __restrict__ out) {
  const int i = blockIdx.x * 256 + threadIdx.x;
  if (i < 2 * BT) stats[i] = __logf(stats[i]);
  if (i == 0) out[0] = 0.6931471805599453f;
}

// Pass 2 (materialized path): JSD terms from stored bf16 logits; one block/row.
__global__ __launch_bounds__(256) void loss_from_blogits(
    const ushort8_t* __restrict__ zs, const ushort8_t* __restrict__ zt,
    const float* __restrict__ lse, float* __restrict__ out) {
  const int row = blockIdx.x;
  const float es = lse[row], et = lse[BT + row];
  const ushort8_t* ps = zs + (size_t)row * (VD / 8);
  const ushort8_t* pt = zt + (size_t)row * (VD / 8);
  float local = 0.f;
  for (int i = threadIdx.x; i < VD / 8; i += 256) {
    const ushort8_t a = ps[i], b = pt[i];
#pragma unroll
    for (int c = 0; c < 8; ++c) {
      const float ls = bf2f(a[c]) - es, lt = bf2f(b[c]) - et;
      const float p = __expf(ls), q = __expf(lt);
      local += p * ls + q * lt - (p + q) * __logf(p + q);
    }
  }
  local += __shfl_xor(local, 1);
  local += __shfl_xor(local, 2);
  local += __shfl_xor(local, 4);
  local += __shfl_xor(local, 8);
  local += __shfl_xor(local, 16);
  local += __shfl_xor(local, 32);
  __shared__ float red[4];
  const int lane = threadIdx.x & 63, wave = threadIdx.x >> 6;
  if (lane == 0) red[wave] = local;
  __syncthreads();
  if (threadIdx.x == 0)
    atomicAdd(out, (red[0] + red[1] + red[2] + red[3]) * (0.5f / BT));
}

// Pass 2 (recompute fallback): both GEMM tiles then joint JSD terms.
template <bool F32SRC>
__global__ __launch_bounds__(256, 2) void gemm_loss(
    const void* Asg, const void* Bsg, const void* Atg, const void* Btg,
    const float* __restrict__ lse, float* __restrict__ out) {
  __shared__ __align__(16) unsigned short As[BM * BK];
  __shared__ __align__(16) unsigned short Bs[BN * BK];
  __shared__ float red[4];
  const int m0 = blockIdx.x * BM;
  const int n0 = blockIdx.y * BN;
  float4_t acc_s[4][4] = {};
  ktile<F32SRC>(Asg, Bsg, acc_s, As, Bs, m0, n0);
  float4_t acc_t[4][4] = {};
  ktile<F32SRC>(Atg, Btg, acc_t, As, Bs, m0, n0);

  const int tid = threadIdx.x;
  const int lane = tid & 63;
  const int wave = tid >> 6;
  const int wm = wave >> 1;
  const int kq = lane >> 4;

  float local = 0.f;
#pragma unroll
  for (int mi = 0; mi < 4; ++mi)
#pragma unroll
    for (int r = 0; r < 4; ++r) {
      const int grow = m0 + wm * 64 + mi * 16 + kq * 4 + r;
      const float es = lse[grow], et = lse[BT + grow];
#pragma unroll
      for (int ni = 0; ni < 4; ++ni) {
        const float ls = acc_s[mi][ni][r] - es;
        const float lt = acc_t[mi][ni][r] - et;
        const float p = __expf(ls), q = __expf(lt);
        local += p * ls + q * lt - (p + q) * __logf(p + q);
      }
    }
  local += __shfl_xor(local, 1);
  local += __shfl_xor(local, 2);
  local += __shfl_xor(local, 4);
  local += __shfl_xor(local, 8);
  local += __shfl_xor(local, 16);
  local += __shfl_xor(local, 32);
  if (lane == 0) red[wave] = local;
  __syncthreads();
  if (tid == 0) atomicAdd(out, (red[0] + red[1] + red[2] + red[3]) * (0.5f / BT));
}

extern "C" void kernel_launch(void* const* d_in, const int* in_sizes, int n_in,
                              void* d_out, int out_size, void* d_ws, size_t ws_size,
                              hipStream_t stream) {
  const float* Xs = (const float*)d_in[0];
  const float* Xt = (const float*)d_in[1];
  const float* Ws = (const float*)d_in[2];
  const float* Wt = (const float*)d_in[3];
  float* out = (float*)d_out;
  char* ws = (char*)d_ws;

  const size_t STATS_B = (size_t)2 * BT * sizeof(float);          // 32 KB
  const size_t XB = (size_t)BT * HD * 2;                          // bf16 X
  const size_t WB = (size_t)VD * HD * 2;                          // bf16 W
  const size_t LOGIT_B = (size_t)2 * BT * VD * 2;                 // bf16 logits (s+t)
  const size_t PRECAST_NEED = STATS_B + 2 * XB + 2 * WB;          // ~296 MB
  const size_t BEST_NEED = PRECAST_NEED + LOGIT_B;                // ~820 MB
  const size_t MID_NEED = STATS_B + LOGIT_B;                      // ~524 MB

  float* stats = (float*)ws;
  hipMemsetAsync(stats, 0, STATS_B, stream);

  const dim3 blk(256);
  const dim3 g1(BT / BM, VD / BN, 2);
  const dim3 g2(BT / BM, VD / BN, 1);
  const int XN4 = BT * HD / 4;
  const int WN4 = VD * HD / 4;

  if (ws_size >= BEST_NEED) {
    // precast bf16 + materialize bf16 logits; 256^2 deep-pipelined GEMM.
    unsigned short* bXs = (unsigned short*)(ws + STATS_B);
    unsigned short* bXt = bXs + (size_t)BT * HD;
    unsigned short* bWs = bXt + (size_t)BT * HD;
    unsigned short* bWt = bWs + (size_t)VD * HD;
    unsigned short* logits = (unsigned short*)(ws + PRECAST_NEED);
    cast4_f32_to_bf16<<<dim3(2048), blk, 0, stream>>>(
        (const float4_t*)Xs, (short4_t*)bXs, (const float4_t*)Xt, (short4_t*)bXt,
        (const float4_t*)Ws, (short4_t*)bWs, (const float4_t*)Wt, (short4_t*)bWt);
    gemm256_pass1<<<dim3((BT / 256) * (VD / 256), 2), dim3(512), 0, stream>>>(
        bXs, bXt, bWs, bWt, stats, logits);
    lse_fix<<<dim3(32), blk, 0, stream>>>(stats, out);
    loss_from_blogits<<<dim3(BT), blk, 0, stream>>>(
        (const ushort8_t*)logits,
        (const ushort8_t*)(logits + (size_t)BT * VD), stats, out);
  } else if (ws_size >= MID_NEED) {
    // no precast: stage f32->bf16 on the fly, materialize bf16 logits
    unsigned short* logits = (unsigned short*)(ws + STATS_B);
    gemm_pass1<true, true><<<g1, blk, 0, stream>>>(Xs, Xt, Ws, Wt, stats, logits);
    lse_fix<<<dim3(32), blk, 0, stream>>>(stats, out);
    loss_from_blogits<<<dim3(BT), blk, 0, stream>>>(
        (const ushort8_t*)logits,
        (const ushort8_t*)(logits + (size_t)BT * VD), stats, out);
  } else if (ws_size >= PRECAST_NEED) {
    // precast bf16, recompute logits in pass 2
    unsigned short* bXs = (unsigned short*)(ws + STATS_B);
    unsigned short* bXt = bXs + (size_t)BT * HD;
    unsigned short* bWs = bXt + (size_t)BT * HD;
    unsigned short* bWt = bWs + (size_t)VD * HD;
    cast4_f32_to_bf16<<<dim3(2048), blk, 0, stream>>>(
        (const float4_t*)Xs, (short4_t*)bXs, (const float4_t*)Xt, (short4_t*)bXt,
        (const float4_t*)Ws, (short4_t*)bWs, (const float4_t*)Wt, (short4_t*)bWt);
    gemm_pass1<false, false><<<g1, blk, 0, stream>>>(bXs, bXt, bWs, bWt, stats, nullptr);
    lse_fix<<<dim3(32), blk, 0, stream>>>(stats, out);
    gemm_loss<false><<<g2, blk, 0, stream>>>(bXs, bWs, bXt, bWt, stats, out);
  } else {
    // minimal-ws fallback: everything on the fly (needs only 32 KB)
    gemm_pass1<true, false><<<g1, blk, 0, stream>>>(Xs, Xt, Ws, Wt, stats, nullptr);
    lse_fix<<<dim3(32), blk, 0, stream>>>(stats, out);
    gemm_loss<true><<<g2, blk, 0, stream>>>(Xs, Ws, Xt, Wt, stats, out);
  }
  (void)in_sizes; (void)n_in; (void)out_size;
}

// Round 4
// 1747.782 us; speedup vs baseline: 1.0285x; 1.0285x over previous
//
#include <hip/hip_runtime.h>
#include <cstdint>

#define BT 4096
#define HD 2048
#define VD 32000

typedef __attribute__((ext_vector_type(4))) float float4_t;
typedef __attribute__((ext_vector_type(4))) short short4_t;
typedef __attribute__((ext_vector_type(8))) short short8_t;
typedef __attribute__((ext_vector_type(8))) unsigned short ushort8_t;

constexpr int BM = 128, BN = 128, BK = 32;

// f32 -> bf16 round-to-nearest-even (inputs are normal, no NaN handling needed)
__device__ __forceinline__ unsigned short f2bf(float f) {
  unsigned u = __float_as_uint(f);
  u += 0x7FFFu + ((u >> 16) & 1u);
  return (unsigned short)(u >> 16);
}

__device__ __forceinline__ float bf2f(unsigned short h) {
  return __uint_as_float((unsigned)h << 16);
}

__device__ __forceinline__ short8_t pack8(float4_t a, float4_t b) {
  short8_t h;
  h[0] = (short)f2bf(a.x); h[1] = (short)f2bf(a.y);
  h[2] = (short)f2bf(a.z); h[3] = (short)f2bf(a.w);
  h[4] = (short)f2bf(b.x); h[5] = (short)f2bf(b.y);
  h[6] = (short)f2bf(b.z); h[7] = (short)f2bf(b.w);
  return h;
}

// async global->LDS, 16B per lane; LDS dest is wave-uniform base + lane*16.
__device__ __forceinline__ void async_copy16(const void* g, void* l) {
  __builtin_amdgcn_global_load_lds(
      (__attribute__((address_space(1))) void*)(uintptr_t)(g),
      (__attribute__((address_space(3))) void*)(uint32_t)(uintptr_t)(l),
      16, 0, 0);
}

__global__ __launch_bounds__(256) void cast_f32_to_bf16(
    const float4_t* __restrict__ in, short4_t* __restrict__ out, int n4) {
  for (int i = blockIdx.x * 256 + threadIdx.x; i < n4; i += gridDim.x * 256) {
    float4_t v = in[i];
    short4_t o;
    o.x = (short)f2bf(v.x); o.y = (short)f2bf(v.y);
    o.z = (short)f2bf(v.z); o.w = (short)f2bf(v.w);
    out[i] = o;
  }
}

// legacy swizzle for 128x128 fallback kernels
__device__ __forceinline__ int swz(int row) { return (row ^ (row >> 2)) & 3; }

// ---------------------------------------------------------------------------
// Legacy 128x128 tile (used by fallback ws paths) — unchanged, verified.
// ---------------------------------------------------------------------------
template <bool F32SRC>
__device__ __forceinline__ void ktile(const void* A, const void* B,
                                      float4_t (&acc)[4][4],
                                      unsigned short* As, unsigned short* Bs,
                                      int m0, int n0) {
  const int tid = threadIdx.x;
  const int lane = tid & 63;
  const int wave = tid >> 6;
  const int wm = wave >> 1, wn = wave & 1;
  const int r0 = tid >> 2, c0 = tid & 3;
  const int cg = c0 ^ swz(r0);
  const int row16 = lane & 15, kq = lane >> 4;
  const int kqs = kq ^ swz(row16);
  const int aoff = (wm * 64 + row16) * BK + kqs * 8;
  const int boff = (wn * 64 + row16) * BK + kqs * 8;
  const int lds0 = __builtin_amdgcn_readfirstlane(wave * 1024);
  const int lds1 = __builtin_amdgcn_readfirstlane(4096 + wave * 1024);

  const unsigned short* Ab = nullptr; const unsigned short* Bb = nullptr;
  const float* Af = nullptr; const float* Bf = nullptr;
  if constexpr (!F32SRC) {
    Ab = (const unsigned short*)A + (size_t)(m0 + r0) * HD + cg * 8;
    Bb = (const unsigned short*)B + (size_t)(n0 + r0) * HD + cg * 8;
  } else {
    Af = (const float*)A + (size_t)(m0 + r0) * HD + cg * 8;
    Bf = (const float*)B + (size_t)(n0 + r0) * HD + cg * 8;
  }

  for (int kb = 0; kb < HD / BK; ++kb) {
    const int ke = kb * BK;
    if constexpr (!F32SRC) {
      async_copy16(Ab + ke, (char*)As + lds0);
      async_copy16(Ab + (size_t)64 * HD + ke, (char*)As + lds1);
      async_copy16(Bb + ke, (char*)Bs + lds0);
      async_copy16(Bb + (size_t)64 * HD + ke, (char*)Bs + lds1);
    } else {
      short8_t hA0 = pack8(*(const float4_t*)(Af + ke), *(const float4_t*)(Af + ke + 4));
      short8_t hA1 = pack8(*(const float4_t*)(Af + (size_t)64 * HD + ke),
                           *(const float4_t*)(Af + (size_t)64 * HD + ke + 4));
      short8_t hB0 = pack8(*(const float4_t*)(Bf + ke), *(const float4_t*)(Bf + ke + 4));
      short8_t hB1 = pack8(*(const float4_t*)(Bf + (size_t)64 * HD + ke),
                           *(const float4_t*)(Bf + (size_t)64 * HD + ke + 4));
      *(short8_t*)((char*)As + tid * 16) = hA0;
      *(short8_t*)((char*)As + 4096 + tid * 16) = hA1;
      *(short8_t*)((char*)Bs + tid * 16) = hB0;
      *(short8_t*)((char*)Bs + 4096 + tid * 16) = hB1;
    }
    __syncthreads();
    short8_t af[4], bfv[4];
#pragma unroll
    for (int mi = 0; mi < 4; ++mi) af[mi] = *(const short8_t*)(As + aoff + mi * 16 * BK);
#pragma unroll
    for (int ni = 0; ni < 4; ++ni) bfv[ni] = *(const short8_t*)(Bs + boff + ni * 16 * BK);
#pragma unroll
    for (int mi = 0; mi < 4; ++mi)
#pragma unroll
      for (int ni = 0; ni < 4; ++ni)
        acc[mi][ni] = __builtin_amdgcn_mfma_f32_16x16x32_bf16(af[mi], bfv[ni], acc[mi][ni], 0, 0, 0);
    __syncthreads();
  }
}

// Pass 1 legacy (fallback paths): 128x128 tile.
template <bool F32SRC, bool STORE>
__global__ __launch_bounds__(256, 2) void gemm_pass1(
    const void* A0, const void* A1, const void* B0, const void* B1,
    float* __restrict__ rowsum, unsigned short* __restrict__ store) {
  __shared__ __align__(16) unsigned short As[BM * BK];
  __shared__ __align__(16) unsigned short Bs[BN * BK];
  const int m0 = blockIdx.x * BM;
  const int n0 = blockIdx.y * BN;
  const int z = blockIdx.z;
  const void* A = z ? A1 : A0;
  const void* B = z ? B1 : B0;
  float4_t acc[4][4] = {};
  ktile<F32SRC>(A, B, acc, As, Bs, m0, n0);

  const int tid = threadIdx.x;
  const int lane = tid & 63;
  const int wave = tid >> 6;
  const int wm = wave >> 1, wn = wave & 1;
  const int row16 = lane & 15, kq = lane >> 4;

  if constexpr (STORE) {
    unsigned short* st = store + (size_t)z * BT * VD;
#pragma unroll
    for (int mi = 0; mi < 4; ++mi)
#pragma unroll
      for (int r = 0; r < 4; ++r) {
        const size_t grow = (size_t)(m0 + wm * 64 + mi * 16 + kq * 4 + r);
        const size_t gc0 = (size_t)(n0 + wn * 64 + row16);
#pragma unroll
        for (int ni = 0; ni < 4; ++ni)
          st[grow * VD + gc0 + ni * 16] = f2bf(acc[mi][ni][r]);
      }
  }

  float* rs = rowsum + z * BT;
#pragma unroll
  for (int mi = 0; mi < 4; ++mi)
#pragma unroll
    for (int r = 0; r < 4; ++r) {
      float s = __expf(acc[mi][0][r]) + __expf(acc[mi][1][r]) +
                __expf(acc[mi][2][r]) + __expf(acc[mi][3][r]);
      s += __shfl_xor(s, 1);
      s += __shfl_xor(s, 2);
      s += __shfl_xor(s, 4);
      s += __shfl_xor(s, 8);
      if (row16 == 0) atomicAdd(&rs[m0 + wm * 64 + mi * 16 + kq * 4 + r], s);
    }
}

// ---------------------------------------------------------------------------
// 256x256 deep-pipelined GEMM, v4 = v2's conflict-free layout + m201's
// two-barriers-per-phase schedule (T2+T3/T4+T5 on a phase-split structure).
//  - M-packed LDS [128 rows][128B], chunk c stores logical c^(R&7): verified
//    conflict-free (round 2: SQ_LDS_BANK_CONFLICT = 0).
//  - Ring of 4 slots, staging 3 K-tiles ahead; vmcnt(8) once per kt (tiles
//    kt+2,kt+3 stay in flight across the barrier) — never drained to 0.
//  - Per kt, 2 phases; each phase: {ds-reads, 1 stage unit (2 gloads),
//    barrier, lgkmcnt(0)+sched_barrier, setprio(1), 16 MFMA, setprio(0),
//    barrier}. Phase-split gives the CU scheduler wave role diversity.
//  - WAR on slot reuse: reads of tile kt-1 are lgkm-drained before its
//    MFMAs, >=1 barrier before STAGE(kt+3) overwrites slot (kt-1)&3.
// ---------------------------------------------------------------------------
constexpr int BK2 = 32;

__global__ __launch_bounds__(512, 2) void gemm256_pass1(
    const unsigned short* __restrict__ bXs, const unsigned short* __restrict__ bXt,
    const unsigned short* __restrict__ bWs, const unsigned short* __restrict__ bWt,
    float* __restrict__ rowsum, unsigned short* __restrict__ store) {
  __shared__ __align__(16) unsigned short lds[4 * 16384];  // 128 KiB

  const int z = blockIdx.y;
  const unsigned short* A = z ? bXt : bXs;
  const unsigned short* B = z ? bWt : bWs;

  // bijective XCD swizzle: 2000 wg/z, 2000 % 8 == 0, 250 per XCD.
  const int o = blockIdx.x;
  const int s = (o & 7) * 250 + (o >> 3);
  const int m0 = (s & 15) * 256;   // m fastest: consecutive s share the W-panel
  const int n0 = (s >> 4) * 256;

  const int tid = threadIdx.x;
  const int lane = tid & 63;
  const int wave = tid >> 6;
  const int wm = wave >> 2;   // 0..1
  const int wn = wave & 3;    // 0..3
  const int row16 = lane & 15, kq = lane >> 4;
  const int rh = row16 >> 1;                       // 3-bit swizzle key (R&7)
  const int cA = (((row16 & 1) << 2) | kq) ^ rh;   // swizzled 16B chunk 0..7

  // Staging source map (inverse-swizzled global addresses; LDS dest linear).
  const int lr = lane >> 3, lc = lane & 7;
  const int cl = lc ^ lr;
  const int k8 = (cl & 3) * 8;
  const int mloc0 = (wave * 2 + 0) * 16 + 2 * lr + (cl >> 2);
  const int mloc1 = (wave * 2 + 1) * 16 + 2 * lr + (cl >> 2);
  const unsigned short* srcA0 = A + (size_t)(m0 + mloc0) * HD + k8;
  const unsigned short* srcA1 = A + (size_t)(m0 + mloc1) * HD + k8;
  const unsigned short* srcB0 = B + (size_t)(n0 + mloc0) * HD + k8;
  const unsigned short* srcB1 = B + (size_t)(n0 + mloc1) * HD + k8;
  const int stA0 = __builtin_amdgcn_readfirstlane((wave * 2 + 0) * 1024);
  const int stA1 = __builtin_amdgcn_readfirstlane((wave * 2 + 1) * 1024);

#define STAGE_A(ktv, slot)                                               \
  do {                                                                   \
    char* _sb = (char*)lds + (slot) * 32768;                             \
    async_copy16(srcA0 + (size_t)(ktv) * BK2, _sb + stA0);               \
    async_copy16(srcA1 + (size_t)(ktv) * BK2, _sb + stA1);               \
  } while (0)
#define STAGE_B(ktv, slot)                                               \
  do {                                                                   \
    char* _sb = (char*)lds + (slot) * 32768 + 16384;                     \
    async_copy16(srcB0 + (size_t)(ktv) * BK2, _sb + stA0);               \
    async_copy16(srcB1 + (size_t)(ktv) * BK2, _sb + stA1);               \
  } while (0)

  // Prologue: stage tiles 0,1,2 (12 loads); wait all but newest 8 -> t0 ready.
  STAGE_A(0, 0); STAGE_B(0, 0);
  STAGE_A(1, 1); STAGE_B(1, 1);
  STAGE_A(2, 2); STAGE_B(2, 2);
  asm volatile("s_waitcnt vmcnt(8)" ::: "memory");
  __builtin_amdgcn_s_barrier();

  float4_t acc[8][4] = {};
  const int aoffE = (wm * 64 + rh) * 64 + cA * 8;
  const int boffE = (wn * 32 + rh) * 64 + cA * 8;

  for (int kt = 0; kt < HD / BK2; ++kt) {
    __builtin_amdgcn_sched_barrier(0);  // nothing crosses the K-tile boundary
    const int buf = kt & 3;
    int ktS = kt + 3;
    if (ktS > HD / BK2 - 1) ktS = HD / BK2 - 1;  // tail: identical rewrite, benign
    const int slotS = ktS & 3;

    const unsigned short* Asl = lds + buf * 16384;
    const unsigned short* Bsl = Asl + 8192;
    short8_t a0[4], a1[4], bfr[4];

    // ---- phase 0: read a0 + b, stage A(kt+3), MFMA m-half 0 ----
#pragma unroll
    for (int mi = 0; mi < 4; ++mi) a0[mi] = *(const short8_t*)(Asl + aoffE + mi * 512);
#pragma unroll
    for (int ni = 0; ni < 4; ++ni) bfr[ni] = *(const short8_t*)(Bsl + boffE + ni * 512);
    STAGE_A(ktS, slotS);
    __builtin_amdgcn_s_barrier();
    asm volatile("s_waitcnt lgkmcnt(0)" ::: "memory");
    __builtin_amdgcn_sched_barrier(0);
    __builtin_amdgcn_s_setprio(1);
#pragma unroll
    for (int mi = 0; mi < 4; ++mi)
#pragma unroll
      for (int ni = 0; ni < 4; ++ni)
        acc[mi][ni] = __builtin_amdgcn_mfma_f32_16x16x32_bf16(a0[mi], bfr[ni], acc[mi][ni], 0, 0, 0);
    __builtin_amdgcn_s_setprio(0);
    __builtin_amdgcn_s_barrier();

    // ---- phase 1: read a1, stage B(kt+3), MFMA m-half 1 (b reused) ----
#pragma unroll
    for (int mi = 0; mi < 4; ++mi) a1[mi] = *(const short8_t*)(Asl + aoffE + (4 + mi) * 512);
    STAGE_B(ktS, slotS);
    __builtin_amdgcn_s_barrier();
    asm volatile("s_waitcnt lgkmcnt(0)" ::: "memory");
    __builtin_amdgcn_sched_barrier(0);
    __builtin_amdgcn_s_setprio(1);
#pragma unroll
    for (int mi = 0; mi < 4; ++mi)
#pragma unroll
      for (int ni = 0; ni < 4; ++ni)
        acc[4 + mi][ni] = __builtin_amdgcn_mfma_f32_16x16x32_bf16(a1[mi], bfr[ni], acc[4 + mi][ni], 0, 0, 0);
    __builtin_amdgcn_s_setprio(0);
    // counted wait: tiles kt+2, kt+3 (8 loads) stay in flight across barrier.
    asm volatile("s_waitcnt vmcnt(8)" ::: "memory");
    __builtin_amdgcn_s_barrier();
  }
#undef STAGE_A
#undef STAGE_B

  // drain remaining async LDS writes before the wave can exit.
  asm volatile("s_waitcnt vmcnt(0)" ::: "memory");

  // Epilogue: store bf16 logits + per-row sum(exp).
  unsigned short* st = store + (size_t)z * BT * VD;
  float* rs = rowsum + z * BT;
#pragma unroll
  for (int mi = 0; mi < 8; ++mi)
#pragma unroll
    for (int r = 0; r < 4; ++r) {
      const size_t grow = (size_t)(m0 + wm * 128 + mi * 16 + kq * 4 + r);
      const size_t gc0 = (size_t)(n0 + wn * 64 + row16);
#pragma unroll
      for (int ni = 0; ni < 4; ++ni)
        st[grow * VD + gc0 + ni * 16] = f2bf(acc[mi][ni][r]);
      float ssum = __expf(acc[mi][0][r]) + __expf(acc[mi][1][r]) +
                   __expf(acc[mi][2][r]) + __expf(acc[mi][3][r]);
      ssum += __shfl_xor(ssum, 1);
      ssum += __shfl_xor(ssum, 2);
      ssum += __shfl_xor(ssum, 4);
      ssum += __shfl_xor(ssum, 8);
      if (row16 == 0) atomicAdd(&rs[grow], ssum);
    }
}

// stats[i] = log(sum_exp) -> LSE; thread 0 seeds out with +ln2 (plain store,
// ordered before pass-2 atomics on the same stream).
__global__ __launch_bounds__(256) void lse_fix(float* __restrict__ stats,
                                               float* __restrict__ out) {
  const int i = blockIdx.x * 256 + threadIdx.x;
  if (i < 2 * BT) stats[i] = __logf(stats[i]);
  if (i == 0) out[0] = 0.6931471805599453f;
}

// Pass 2 (materialized path): JSD terms from stored bf16 logits; one block/row.
__global__ __launch_bounds__(256) void loss_from_blogits(
    const ushort8_t* __restrict__ zs, const ushort8_t* __restrict__ zt,
    const float* __restrict__ lse, float* __restrict__ out) {
  const int row = blockIdx.x;
  const float es = lse[row], et = lse[BT + row];
  const ushort8_t* ps = zs + (size_t)row * (VD / 8);
  const ushort8_t* pt = zt + (size_t)row * (VD / 8);
  float local = 0.f;
  for (int i = threadIdx.x; i < VD / 8; i += 256) {
    const ushort8_t a = ps[i], b = pt[i];
#pragma unroll
    for (int c = 0; c < 8; ++c) {
      const float ls = bf2f(a[c]) - es, lt = bf2f(b[c]) - et;
      const float p = __expf(ls), q = __expf(lt);
      local += p * ls + q * lt - (p + q) * __logf(p + q);
    }
  }
  local += __shfl_xor(local, 1);
  local += __shfl_xor(local, 2);
  local += __shfl_xor(local, 4);
  local += __shfl_xor(local, 8);
  local += __shfl_xor(local, 16);
  local += __shfl_xor(local, 32);
  __shared__ float red[4];
  const int lane = threadIdx.x & 63, wave = threadIdx.x >> 6;
  if (lane == 0) red[wave] = local;
  __syncthreads();
  if (threadIdx.x == 0)
    atomicAdd(out, (red[0] + red[1] + red[2] + red[3]) * (0.5f / BT));
}

// Pass 2 (recompute fallback): both GEMM tiles then joint JSD terms.
template <bool F32SRC>
__global__ __launch_bounds__(256, 2) void gemm_loss(
    const void* Asg, const void* Bsg, const void* Atg, const void* Btg,
    const float* __restrict__ lse, float* __restrict__ out) {
  __shared__ __align__(16) unsigned short As[BM * BK];
  __shared__ __align__(16) unsigned short Bs[BN * BK];
  __shared__ float red[4];
  const int m0 = blockIdx.x * BM;
  const int n0 = blockIdx.y * BN;
  float4_t acc_s[4][4] = {};
  ktile<F32SRC>(Asg, Bsg, acc_s, As, Bs, m0, n0);
  float4_t acc_t[4][4] = {};
  ktile<F32SRC>(Atg, Btg, acc_t, As, Bs, m0, n0);

  const int tid = threadIdx.x;
  const int lane = tid & 63;
  const int wave = tid >> 6;
  const int wm = wave >> 1;
  const int kq = lane >> 4;

  float local = 0.f;
#pragma unroll
  for (int mi = 0; mi < 4; ++mi)
#pragma unroll
    for (int r = 0; r < 4; ++r) {
      const int grow = m0 + wm * 64 + mi * 16 + kq * 4 + r;
      const float es = lse[grow], et = lse[BT + grow];
#pragma unroll
      for (int ni = 0; ni < 4; ++ni) {
        const float ls = acc_s[mi][ni][r] - es;
        const float lt = acc_t[mi][ni][r] - et;
        const float p = __expf(ls), q = __expf(lt);
        local += p * ls + q * lt - (p + q) * __logf(p + q);
      }
    }
  local += __shfl_xor(local, 1);
  local += __shfl_xor(local, 2);
  local += __shfl_xor(local, 4);
  local += __shfl_xor(local, 8);
  local += __shfl_xor(local, 16);
  local += __shfl_xor(local, 32);
  if (lane == 0) red[wave] = local;
  __syncthreads();
  if (tid == 0) atomicAdd(out, (red[0] + red[1] + red[2] + red[3]) * (0.5f / BT));
}

extern "C" void kernel_launch(void* const* d_in, const int* in_sizes, int n_in,
                              void* d_out, int out_size, void* d_ws, size_t ws_size,
                              hipStream_t stream) {
  const float* Xs = (const float*)d_in[0];
  const float* Xt = (const float*)d_in[1];
  const float* Ws = (const float*)d_in[2];
  const float* Wt = (const float*)d_in[3];
  float* out = (float*)d_out;
  char* ws = (char*)d_ws;

  const size_t STATS_B = (size_t)2 * BT * sizeof(float);          // 32 KB
  const size_t XB = (size_t)BT * HD * 2;                          // bf16 X
  const size_t WB = (size_t)VD * HD * 2;                          // bf16 W
  const size_t LOGIT_B = (size_t)2 * BT * VD * 2;                 // bf16 logits (s+t)
  const size_t PRECAST_NEED = STATS_B + 2 * XB + 2 * WB;          // ~296 MB
  const size_t BEST_NEED = PRECAST_NEED + LOGIT_B;                // ~820 MB
  const size_t MID_NEED = STATS_B + LOGIT_B;                      // ~524 MB

  float* stats = (float*)ws;
  hipMemsetAsync(stats, 0, STATS_B, stream);

  const dim3 blk(256);
  const dim3 g1(BT / BM, VD / BN, 2);
  const dim3 g2(BT / BM, VD / BN, 1);
  const int XN4 = BT * HD / 4;
  const int WN4 = VD * HD / 4;

  if (ws_size >= BEST_NEED) {
    // precast bf16 + materialize bf16 logits; 256^2 deep-pipelined GEMM.
    unsigned short* bXs = (unsigned short*)(ws + STATS_B);
    unsigned short* bXt = bXs + (size_t)BT * HD;
    unsigned short* bWs = bXt + (size_t)BT * HD;
    unsigned short* bWt = bWs + (size_t)VD * HD;
    unsigned short* logits = (unsigned short*)(ws + PRECAST_NEED);
    cast_f32_to_bf16<<<dim3(512), blk, 0, stream>>>((const float4_t*)Xs, (short4_t*)bXs, XN4);
    cast_f32_to_bf16<<<dim3(512), blk, 0, stream>>>((const float4_t*)Xt, (short4_t*)bXt, XN4);
    cast_f32_to_bf16<<<dim3(2048), blk, 0, stream>>>((const float4_t*)Ws, (short4_t*)bWs, WN4);
    cast_f32_to_bf16<<<dim3(2048), blk, 0, stream>>>((const float4_t*)Wt, (short4_t*)bWt, WN4);
    gemm256_pass1<<<dim3((BT / 256) * (VD / 256), 2), dim3(512), 0, stream>>>(
        bXs, bXt, bWs, bWt, stats, logits);
    lse_fix<<<dim3(32), blk, 0, stream>>>(stats, out);
    loss_from_blogits<<<dim3(BT), blk, 0, stream>>>(
        (const ushort8_t*)logits,
        (const ushort8_t*)(logits + (size_t)BT * VD), stats, out);
  } else if (ws_size >= MID_NEED) {
    // no precast: stage f32->bf16 on the fly, materialize bf16 logits
    unsigned short* logits = (unsigned short*)(ws + STATS_B);
    gemm_pass1<true, true><<<g1, blk, 0, stream>>>(Xs, Xt, Ws, Wt, stats, logits);
    lse_fix<<<dim3(32), blk, 0, stream>>>(stats, out);
    loss_from_blogits<<<dim3(BT), blk, 0, stream>>>(
        (const ushort8_t*)logits,
        (const ushort8_t*)(logits + (size_t)BT * VD), stats, out);
  } else if (ws_size >= PRECAST_NEED) {
    // precast bf16, recompute logits in pass 2
    unsigned short* bXs = (unsigned short*)(ws + STATS_B);
    unsigned short* bXt = bXs + (size_t)BT * HD;
    unsigned short* bWs = bXt + (size_t)BT * HD;
    unsigned short* bWt = bWs + (size_t)VD * HD;
    cast_f32_to_bf16<<<dim3(512), blk, 0, stream>>>((const float4_t*)Xs, (short4_t*)bXs, XN4);
    cast_f32_to_bf16<<<dim3(512), blk, 0, stream>>>((const float4_t*)Xt, (short4_t*)bXt, XN4);
    cast_f32_to_bf16<<<dim3(2048), blk, 0, stream>>>((const float4_t*)Ws, (short4_t*)bWs, WN4);
    cast_f32_to_bf16<<<dim3(2048), blk, 0, stream>>>((const float4_t*)Wt, (short4_t*)bWt, WN4);
    gemm_pass1<false, false><<<g1, blk, 0, stream>>>(bXs, bXt, bWs, bWt, stats, nullptr);
    lse_fix<<<dim3(32), blk, 0, stream>>>(stats, out);
    gemm_loss<false><<<g2, blk, 0, stream>>>(bXs, bWs, bXt, bWt, stats, out);
  } else {
    // minimal-ws fallback: everything on the fly (needs only 32 KB)
    gemm_pass1<true, false><<<g1, blk, 0, stream>>>(Xs, Xt, Ws, Wt, stats, nullptr);
    lse_fix<<<dim3(32), blk, 0, stream>>>(stats, out);
    gemm_loss<true><<<g2, blk, 0, stream>>>(Xs, Ws, Xt, Wt, stats, out);
  }
  (void)in_sizes; (void)n_in; (void)out_size;
}

// Round 5
// 1738.547 us; speedup vs baseline: 1.0339x; 1.0053x over previous
//
#include <hip/hip_runtime.h>
#include <cstdint>

#define BT 4096
#define HD 2048
#define VD 32000

typedef __attribute__((ext_vector_type(4))) float float4_t;
typedef __attribute__((ext_vector_type(4))) short short4_t;
typedef __attribute__((ext_vector_type(8))) short short8_t;
typedef __attribute__((ext_vector_type(8))) unsigned short ushort8_t;

constexpr int BM = 128, BN = 128, BK = 32;

// f32 -> bf16 round-to-nearest-even (inputs are normal, no NaN handling needed)
__device__ __forceinline__ unsigned short f2bf(float f) {
  unsigned u = __float_as_uint(f);
  u += 0x7FFFu + ((u >> 16) & 1u);
  return (unsigned short)(u >> 16);
}

__device__ __forceinline__ float bf2f(unsigned short h) {
  return __uint_as_float((unsigned)h << 16);
}

__device__ __forceinline__ short8_t pack8(float4_t a, float4_t b) {
  short8_t h;
  h[0] = (short)f2bf(a.x); h[1] = (short)f2bf(a.y);
  h[2] = (short)f2bf(a.z); h[3] = (short)f2bf(a.w);
  h[4] = (short)f2bf(b.x); h[5] = (short)f2bf(b.y);
  h[6] = (short)f2bf(b.z); h[7] = (short)f2bf(b.w);
  return h;
}

// async global->LDS, 16B per lane; LDS dest is wave-uniform base + lane*16.
__device__ __forceinline__ void async_copy16(const void* g, void* l) {
  __builtin_amdgcn_global_load_lds(
      (__attribute__((address_space(1))) void*)(uintptr_t)(g),
      (__attribute__((address_space(3))) void*)(uint32_t)(uintptr_t)(l),
      16, 0, 0);
}

__global__ __launch_bounds__(256) void cast_f32_to_bf16(
    const float4_t* __restrict__ in, short4_t* __restrict__ out, int n4) {
  for (int i = blockIdx.x * 256 + threadIdx.x; i < n4; i += gridDim.x * 256) {
    float4_t v = in[i];
    short4_t o;
    o.x = (short)f2bf(v.x); o.y = (short)f2bf(v.y);
    o.z = (short)f2bf(v.z); o.w = (short)f2bf(v.w);
    out[i] = o;
  }
}

// legacy swizzle for 128x128 fallback kernels
__device__ __forceinline__ int swz(int row) { return (row ^ (row >> 2)) & 3; }

// ---------------------------------------------------------------------------
// Legacy 128x128 tile (used by fallback ws paths) — unchanged, verified.
// ---------------------------------------------------------------------------
template <bool F32SRC>
__device__ __forceinline__ void ktile(const void* A, const void* B,
                                      float4_t (&acc)[4][4],
                                      unsigned short* As, unsigned short* Bs,
                                      int m0, int n0) {
  const int tid = threadIdx.x;
  const int lane = tid & 63;
  const int wave = tid >> 6;
  const int wm = wave >> 1, wn = wave & 1;
  const int r0 = tid >> 2, c0 = tid & 3;
  const int cg = c0 ^ swz(r0);
  const int row16 = lane & 15, kq = lane >> 4;
  const int kqs = kq ^ swz(row16);
  const int aoff = (wm * 64 + row16) * BK + kqs * 8;
  const int boff = (wn * 64 + row16) * BK + kqs * 8;
  const int lds0 = __builtin_amdgcn_readfirstlane(wave * 1024);
  const int lds1 = __builtin_amdgcn_readfirstlane(4096 + wave * 1024);

  const unsigned short* Ab = nullptr; const unsigned short* Bb = nullptr;
  const float* Af = nullptr; const float* Bf = nullptr;
  if constexpr (!F32SRC) {
    Ab = (const unsigned short*)A + (size_t)(m0 + r0) * HD + cg * 8;
    Bb = (const unsigned short*)B + (size_t)(n0 + r0) * HD + cg * 8;
  } else {
    Af = (const float*)A + (size_t)(m0 + r0) * HD + cg * 8;
    Bf = (const float*)B + (size_t)(n0 + r0) * HD + cg * 8;
  }

  for (int kb = 0; kb < HD / BK; ++kb) {
    const int ke = kb * BK;
    if constexpr (!F32SRC) {
      async_copy16(Ab + ke, (char*)As + lds0);
      async_copy16(Ab + (size_t)64 * HD + ke, (char*)As + lds1);
      async_copy16(Bb + ke, (char*)Bs + lds0);
      async_copy16(Bb + (size_t)64 * HD + ke, (char*)Bs + lds1);
    } else {
      short8_t hA0 = pack8(*(const float4_t*)(Af + ke), *(const float4_t*)(Af + ke + 4));
      short8_t hA1 = pack8(*(const float4_t*)(Af + (size_t)64 * HD + ke),
                           *(const float4_t*)(Af + (size_t)64 * HD + ke + 4));
      short8_t hB0 = pack8(*(const float4_t*)(Bf + ke), *(const float4_t*)(Bf + ke + 4));
      short8_t hB1 = pack8(*(const float4_t*)(Bf + (size_t)64 * HD + ke),
                           *(const float4_t*)(Bf + (size_t)64 * HD + ke + 4));
      *(short8_t*)((char*)As + tid * 16) = hA0;
      *(short8_t*)((char*)As + 4096 + tid * 16) = hA1;
      *(short8_t*)((char*)Bs + tid * 16) = hB0;
      *(short8_t*)((char*)Bs + 4096 + tid * 16) = hB1;
    }
    __syncthreads();
    short8_t af[4], bfv[4];
#pragma unroll
    for (int mi = 0; mi < 4; ++mi) af[mi] = *(const short8_t*)(As + aoff + mi * 16 * BK);
#pragma unroll
    for (int ni = 0; ni < 4; ++ni) bfv[ni] = *(const short8_t*)(Bs + boff + ni * 16 * BK);
#pragma unroll
    for (int mi = 0; mi < 4; ++mi)
#pragma unroll
      for (int ni = 0; ni < 4; ++ni)
        acc[mi][ni] = __builtin_amdgcn_mfma_f32_16x16x32_bf16(af[mi], bfv[ni], acc[mi][ni], 0, 0, 0);
    __syncthreads();
  }
}

// Pass 1 legacy (fallback paths): 128x128 tile.
template <bool F32SRC, bool STORE>
__global__ __launch_bounds__(256, 2) void gemm_pass1(
    const void* A0, const void* A1, const void* B0, const void* B1,
    float* __restrict__ rowsum, unsigned short* __restrict__ store) {
  __shared__ __align__(16) unsigned short As[BM * BK];
  __shared__ __align__(16) unsigned short Bs[BN * BK];
  const int m0 = blockIdx.x * BM;
  const int n0 = blockIdx.y * BN;
  const int z = blockIdx.z;
  const void* A = z ? A1 : A0;
  const void* B = z ? B1 : B0;
  float4_t acc[4][4] = {};
  ktile<F32SRC>(A, B, acc, As, Bs, m0, n0);

  const int tid = threadIdx.x;
  const int lane = tid & 63;
  const int wave = tid >> 6;
  const int wm = wave >> 1, wn = wave & 1;
  const int row16 = lane & 15, kq = lane >> 4;

  if constexpr (STORE) {
    unsigned short* st = store + (size_t)z * BT * VD;
#pragma unroll
    for (int mi = 0; mi < 4; ++mi)
#pragma unroll
      for (int r = 0; r < 4; ++r) {
        const size_t grow = (size_t)(m0 + wm * 64 + mi * 16 + kq * 4 + r);
        const size_t gc0 = (size_t)(n0 + wn * 64 + row16);
#pragma unroll
        for (int ni = 0; ni < 4; ++ni)
          st[grow * VD + gc0 + ni * 16] = f2bf(acc[mi][ni][r]);
      }
  }

  float* rs = rowsum + z * BT;
#pragma unroll
  for (int mi = 0; mi < 4; ++mi)
#pragma unroll
    for (int r = 0; r < 4; ++r) {
      float s = __expf(acc[mi][0][r]) + __expf(acc[mi][1][r]) +
                __expf(acc[mi][2][r]) + __expf(acc[mi][3][r]);
      s += __shfl_xor(s, 1);
      s += __shfl_xor(s, 2);
      s += __shfl_xor(s, 4);
      s += __shfl_xor(s, 8);
      if (row16 == 0) atomicAdd(&rs[m0 + wm * 64 + mi * 16 + kq * 4 + r], s);
    }
}

// ---------------------------------------------------------------------------
// 256x256 deep-pipelined GEMM, v5: cross-tile frag pipelining (reads of tile
// kt+1 fly under MFMA of tile kt).
//  - M-packed LDS [128 rows][128B], chunk c stores logical c^(R&7): verified
//    conflict-free (round 2: SQ_LDS_BANK_CONFLICT = 0).
//  - Ring of 4 slots, staging 3 K-tiles ahead; ONE vmcnt(8)+barrier per kt.
//    Tile kt+1 was staged at body kt-2; body kt's vmcnt(8) retires it.
//  - Body kt: {STAGE(kt+3); read a1(kt); MFMA half0 (operands a0/b read in
//    body kt-1 — zero wait, issues immediately); vmcnt(8); barrier; read
//    a0/b(kt+1) [no wait -- they complete under half1 and next half0];
//    MFMA half1 (counted lgkm wait on a1 only — the 8 newer reads stay
//    outstanding)}. LDS reads flow continuously under the matrix pipe.
//  - NO explicit lgkmcnt: compiler precise in-order waits do the counting.
//  - WAR: reads of tile kt-1 are lgkm-complete before barrier(kt-1), which
//    precedes STAGE(kt+3) into slot (kt-1)&3. Tail stages clamp to tile 63
//    (redundant rewrites into dead slots, benign); last body skips next-reads.
// ---------------------------------------------------------------------------
constexpr int BK2 = 32;

__global__ __launch_bounds__(512, 2) void gemm256_pass1(
    const unsigned short* __restrict__ bXs, const unsigned short* __restrict__ bXt,
    const unsigned short* __restrict__ bWs, const unsigned short* __restrict__ bWt,
    float* __restrict__ rowsum, unsigned short* __restrict__ store) {
  __shared__ __align__(16) unsigned short lds[4 * 16384];  // 128 KiB

  const int z = blockIdx.y;
  const unsigned short* A = z ? bXt : bXs;
  const unsigned short* B = z ? bWt : bWs;

  // bijective XCD swizzle: 2000 wg/z, 2000 % 8 == 0, 250 per XCD.
  const int o = blockIdx.x;
  const int s = (o & 7) * 250 + (o >> 3);
  const int m0 = (s & 15) * 256;   // m fastest: consecutive s share the W-panel
  const int n0 = (s >> 4) * 256;

  const int tid = threadIdx.x;
  const int lane = tid & 63;
  const int wave = tid >> 6;
  const int wm = wave >> 2;   // 0..1
  const int wn = wave & 3;    // 0..3
  const int row16 = lane & 15, kq = lane >> 4;
  const int rh = row16 >> 1;                       // 3-bit swizzle key (R&7)
  const int cA = (((row16 & 1) << 2) | kq) ^ rh;   // swizzled 16B chunk 0..7

  // Staging source map (inverse-swizzled global addresses; LDS dest linear).
  const int lr = lane >> 3, lc = lane & 7;
  const int cl = lc ^ lr;
  const int k8 = (cl & 3) * 8;
  const int mloc0 = (wave * 2 + 0) * 16 + 2 * lr + (cl >> 2);
  const int mloc1 = (wave * 2 + 1) * 16 + 2 * lr + (cl >> 2);
  const unsigned short* srcA0 = A + (size_t)(m0 + mloc0) * HD + k8;
  const unsigned short* srcA1 = A + (size_t)(m0 + mloc1) * HD + k8;
  const unsigned short* srcB0 = B + (size_t)(n0 + mloc0) * HD + k8;
  const unsigned short* srcB1 = B + (size_t)(n0 + mloc1) * HD + k8;
  const int stA0 = __builtin_amdgcn_readfirstlane((wave * 2 + 0) * 1024);
  const int stA1 = __builtin_amdgcn_readfirstlane((wave * 2 + 1) * 1024);

#define STAGE(ktv, slot)                                                 \
  do {                                                                   \
    char* _sb = (char*)lds + (slot) * 32768;                             \
    async_copy16(srcA0 + (size_t)(ktv) * BK2, _sb + stA0);               \
    async_copy16(srcA1 + (size_t)(ktv) * BK2, _sb + stA1);               \
    async_copy16(srcB0 + (size_t)(ktv) * BK2, _sb + 16384 + stA0);       \
    async_copy16(srcB1 + (size_t)(ktv) * BK2, _sb + 16384 + stA1);       \
  } while (0)

  float4_t acc[8][4] = {};
  const int aoffE = (wm * 64 + rh) * 64 + cA * 8;
  const int boffE = (wn * 32 + rh) * 64 + cA * 8;

  short8_t a0A[4], bA[4], a0B[4], bB[4];

  // Prologue: stage tiles 0,1,2 (12 loads); vmcnt(8) retires tile 0; read
  // tile 0's a0/b frags into set A.
  STAGE(0, 0);
  STAGE(1, 1);
  STAGE(2, 2);
  asm volatile("s_waitcnt vmcnt(8)" ::: "memory");
  __builtin_amdgcn_s_barrier();
  __builtin_amdgcn_sched_barrier(0);
#pragma unroll
  for (int mi = 0; mi < 4; ++mi) a0A[mi] = *(const short8_t*)(lds + aoffE + mi * 512);
#pragma unroll
  for (int ni = 0; ni < 4; ++ni) bA[ni] = *(const short8_t*)(lds + 8192 + boffE + ni * 512);

#define KBODY(KT, A0C, BC, A0N, BN, DO_NEXT)                                  \
  do {                                                                        \
    const int _ktS = ((KT) + 3 > 63) ? 63 : (KT) + 3;                         \
    STAGE(_ktS, _ktS & 3);                                                    \
    const unsigned short* _As = lds + ((KT) & 3) * 16384;                     \
    short8_t _a1[4];                                                          \
    _Pragma("unroll")                                                         \
    for (int mi = 0; mi < 4; ++mi)                                            \
      _a1[mi] = *(const short8_t*)(_As + aoffE + (4 + mi) * 512);             \
    __builtin_amdgcn_s_setprio(1);                                            \
    _Pragma("unroll")                                                         \
    for (int mi = 0; mi < 4; ++mi)                                            \
      _Pragma("unroll")                                                       \
      for (int ni = 0; ni < 4; ++ni)                                          \
        acc[mi][ni] = __builtin_amdgcn_mfma_f32_16x16x32_bf16(                \
            A0C[mi], BC[ni], acc[mi][ni], 0, 0, 0);                           \
    __builtin_amdgcn_s_setprio(0);                                            \
    asm volatile("s_waitcnt vmcnt(8)" ::: "memory");                          \
    __builtin_amdgcn_s_barrier();                                             \
    __builtin_amdgcn_sched_barrier(0);                                        \
    if (DO_NEXT) {                                                            \
      const unsigned short* _An = lds + (((KT) + 1) & 3) * 16384;             \
      const unsigned short* _Bn = _An + 8192;                                 \
      _Pragma("unroll")                                                       \
      for (int mi = 0; mi < 4; ++mi)                                          \
        A0N[mi] = *(const short8_t*)(_An + aoffE + mi * 512);                 \
      _Pragma("unroll")                                                       \
      for (int ni = 0; ni < 4; ++ni)                                          \
        BN[ni] = *(const short8_t*)(_Bn + boffE + ni * 512);                  \
    }                                                                         \
    __builtin_amdgcn_s_setprio(1);                                            \
    _Pragma("unroll")                                                         \
    for (int mi = 0; mi < 4; ++mi)                                            \
      _Pragma("unroll")                                                       \
      for (int ni = 0; ni < 4; ++ni)                                          \
        acc[4 + mi][ni] = __builtin_amdgcn_mfma_f32_16x16x32_bf16(            \
            _a1[mi], BC[ni], acc[4 + mi][ni], 0, 0, 0);                       \
    __builtin_amdgcn_s_setprio(0);                                            \
  } while (0)

#pragma unroll 1
  for (int kt = 0; kt < 62; kt += 2) {
    KBODY(kt,     a0A, bA, a0B, bB, 1);
    KBODY(kt + 1, a0B, bB, a0A, bA, 1);
  }
  KBODY(62, a0A, bA, a0B, bB, 1);
  KBODY(63, a0B, bB, a0A, bA, 0);
#undef KBODY
#undef STAGE

  // drain remaining async LDS writes before the wave can exit.
  asm volatile("s_waitcnt vmcnt(0)" ::: "memory");

  // Epilogue: store bf16 logits + per-row sum(exp).
  unsigned short* st = store + (size_t)z * BT * VD;
  float* rs = rowsum + z * BT;
#pragma unroll
  for (int mi = 0; mi < 8; ++mi)
#pragma unroll
    for (int r = 0; r < 4; ++r) {
      const size_t grow = (size_t)(m0 + wm * 128 + mi * 16 + kq * 4 + r);
      const size_t gc0 = (size_t)(n0 + wn * 64 + row16);
#pragma unroll
      for (int ni = 0; ni < 4; ++ni)
        st[grow * VD + gc0 + ni * 16] = f2bf(acc[mi][ni][r]);
      float ssum = __expf(acc[mi][0][r]) + __expf(acc[mi][1][r]) +
                   __expf(acc[mi][2][r]) + __expf(acc[mi][3][r]);
      ssum += __shfl_xor(ssum, 1);
      ssum += __shfl_xor(ssum, 2);
      ssum += __shfl_xor(ssum, 4);
      ssum += __shfl_xor(ssum, 8);
      if (row16 == 0) atomicAdd(&rs[grow], ssum);
    }
}

// stats[i] = log(sum_exp) -> LSE; thread 0 seeds out with +ln2 (plain store,
// ordered before pass-2 atomics on the same stream).
__global__ __launch_bounds__(256) void lse_fix(float* __restrict__ stats,
                                               float* __restrict__ out) {
  const int i = blockIdx.x * 256 + threadIdx.x;
  if (i < 2 * BT) stats[i] = __logf(stats[i]);
  if (i == 0) out[0] = 0.6931471805599453f;
}

// Pass 2 (materialized path): JSD terms from stored bf16 logits; one block/row.
__global__ __launch_bounds__(256) void loss_from_blogits(
    const ushort8_t* __restrict__ zs, const ushort8_t* __restrict__ zt,
    const float* __restrict__ lse, float* __restrict__ out) {
  const int row = blockIdx.x;
  const float es = lse[row], et = lse[BT + row];
  const ushort8_t* ps = zs + (size_t)row * (VD / 8);
  const ushort8_t* pt = zt + (size_t)row * (VD / 8);
  float local = 0.f;
  for (int i = threadIdx.x; i < VD / 8; i += 256) {
    const ushort8_t a = ps[i], b = pt[i];
#pragma unroll
    for (int c = 0; c < 8; ++c) {
      const float ls = bf2f(a[c]) - es, lt = bf2f(b[c]) - et;
      const float p = __expf(ls), q = __expf(lt);
      local += p * ls + q * lt - (p + q) * __logf(p + q);
    }
  }
  local += __shfl_xor(local, 1);
  local += __shfl_xor(local, 2);
  local += __shfl_xor(local, 4);
  local += __shfl_xor(local, 8);
  local += __shfl_xor(local, 16);
  local += __shfl_xor(local, 32);
  __shared__ float red[4];
  const int lane = threadIdx.x & 63, wave = threadIdx.x >> 6;
  if (lane == 0) red[wave] = local;
  __syncthreads();
  if (threadIdx.x == 0)
    atomicAdd(out, (red[0] + red[1] + red[2] + red[3]) * (0.5f / BT));
}

// Pass 2 (recompute fallback): both GEMM tiles then joint JSD terms.
template <bool F32SRC>
__global__ __launch_bounds__(256, 2) void gemm_loss(
    const void* Asg, const void* Bsg, const void* Atg, const void* Btg,
    const float* __restrict__ lse, float* __restrict__ out) {
  __shared__ __align__(16) unsigned short As[BM * BK];
  __shared__ __align__(16) unsigned short Bs[BN * BK];
  __shared__ float red[4];
  const int m0 = blockIdx.x * BM;
  const int n0 = blockIdx.y * BN;
  float4_t acc_s[4][4] = {};
  ktile<F32SRC>(Asg, Bsg, acc_s, As, Bs, m0, n0);
  float4_t acc_t[4][4] = {};
  ktile<F32SRC>(Atg, Btg, acc_t, As, Bs, m0, n0);

  const int tid = threadIdx.x;
  const int lane = tid & 63;
  const int wave = tid >> 6;
  const int wm = wave >> 1;
  const int kq = lane >> 4;

  float local = 0.f;
#pragma unroll
  for (int mi = 0; mi < 4; ++mi)
#pragma unroll
    for (int r = 0; r < 4; ++r) {
      const int grow = m0 + wm * 64 + mi * 16 + kq * 4 + r;
      const float es = lse[grow], et = lse[BT + grow];
#pragma unroll
      for (int ni = 0; ni < 4; ++ni) {
        const float ls = acc_s[mi][ni][r] - es;
        const float lt = acc_t[mi][ni][r] - et;
        const float p = __expf(ls), q = __expf(lt);
        local += p * ls + q * lt - (p + q) * __logf(p + q);
      }
    }
  local += __shfl_xor(local, 1);
  local += __shfl_xor(local, 2);
  local += __shfl_xor(local, 4);
  local += __shfl_xor(local, 8);
  local += __shfl_xor(local, 16);
  local += __shfl_xor(local, 32);
  if (lane == 0) red[wave] = local;
  __syncthreads();
  if (tid == 0) atomicAdd(out, (red[0] + red[1] + red[2] + red[3]) * (0.5f / BT));
}

extern "C" void kernel_launch(void* const* d_in, const int* in_sizes, int n_in,
                              void* d_out, int out_size, void* d_ws, size_t ws_size,
                              hipStream_t stream) {
  const float* Xs = (const float*)d_in[0];
  const float* Xt = (const float*)d_in[1];
  const float* Ws = (const float*)d_in[2];
  const float* Wt = (const float*)d_in[3];
  float* out = (float*)d_out;
  char* ws = (char*)d_ws;

  const size_t STATS_B = (size_t)2 * BT * sizeof(float);          // 32 KB
  const size_t XB = (size_t)BT * HD * 2;                          // bf16 X
  const size_t WB = (size_t)VD * HD * 2;                          // bf16 W
  const size_t LOGIT_B = (size_t)2 * BT * VD * 2;                 // bf16 logits (s+t)
  const size_t PRECAST_NEED = STATS_B + 2 * XB + 2 * WB;          // ~296 MB
  const size_t BEST_NEED = PRECAST_NEED + LOGIT_B;                // ~820 MB
  const size_t MID_NEED = STATS_B + LOGIT_B;                      // ~524 MB

  float* stats = (float*)ws;
  hipMemsetAsync(stats, 0, STATS_B, stream);

  const dim3 blk(256);
  const dim3 g1(BT / BM, VD / BN, 2);
  const dim3 g2(BT / BM, VD / BN, 1);
  const int XN4 = BT * HD / 4;
  const int WN4 = VD * HD / 4;

  if (ws_size >= BEST_NEED) {
    // precast bf16 + materialize bf16 logits; 256^2 deep-pipelined GEMM.
    unsigned short* bXs = (unsigned short*)(ws + STATS_B);
    unsigned short* bXt = bXs + (size_t)BT * HD;
    unsigned short* bWs = bXt + (size_t)BT * HD;
    unsigned short* bWt = bWs + (size_t)VD * HD;
    unsigned short* logits = (unsigned short*)(ws + PRECAST_NEED);
    cast_f32_to_bf16<<<dim3(512), blk, 0, stream>>>((const float4_t*)Xs, (short4_t*)bXs, XN4);
    cast_f32_to_bf16<<<dim3(512), blk, 0, stream>>>((const float4_t*)Xt, (short4_t*)bXt, XN4);
    cast_f32_to_bf16<<<dim3(2048), blk, 0, stream>>>((const float4_t*)Ws, (short4_t*)bWs, WN4);
    cast_f32_to_bf16<<<dim3(2048), blk, 0, stream>>>((const float4_t*)Wt, (short4_t*)bWt, WN4);
    gemm256_pass1<<<dim3((BT / 256) * (VD / 256), 2), dim3(512), 0, stream>>>(
        bXs, bXt, bWs, bWt, stats, logits);
    lse_fix<<<dim3(32), blk, 0, stream>>>(stats, out);
    loss_from_blogits<<<dim3(BT), blk, 0, stream>>>(
        (const ushort8_t*)logits,
        (const ushort8_t*)(logits + (size_t)BT * VD), stats, out);
  } else if (ws_size >= MID_NEED) {
    // no precast: stage f32->bf16 on the fly, materialize bf16 logits
    unsigned short* logits = (unsigned short*)(ws + STATS_B);
    gemm_pass1<true, true><<<g1, blk, 0, stream>>>(Xs, Xt, Ws, Wt, stats, logits);
    lse_fix<<<dim3(32), blk, 0, stream>>>(stats, out);
    loss_from_blogits<<<dim3(BT), blk, 0, stream>>>(
        (const ushort8_t*)logits,
        (const ushort8_t*)(logits + (size_t)BT * VD), stats, out);
  } else if (ws_size >= PRECAST_NEED) {
    // precast bf16, recompute logits in pass 2
    unsigned short* bXs = (unsigned short*)(ws + STATS_B);
    unsigned short* bXt = bXs + (size_t)BT * HD;
    unsigned short* bWs = bXt + (size_t)BT * HD;
    unsigned short* bWt = bWs + (size_t)VD * HD;
    cast_f32_to_bf16<<<dim3(512), blk, 0, stream>>>((const float4_t*)Xs, (short4_t*)bXs, XN4);
    cast_f32_to_bf16<<<dim3(512), blk, 0, stream>>>((const float4_t*)Xt, (short4_t*)bXt, XN4);
    cast_f32_to_bf16<<<dim3(2048), blk, 0, stream>>>((const float4_t*)Ws, (short4_t*)bWs, WN4);
    cast_f32_to_bf16<<<dim3(2048), blk, 0, stream>>>((const float4_t*)Wt, (short4_t*)bWt, WN4);
    gemm_pass1<false, false><<<g1, blk, 0, stream>>>(bXs, bXt, bWs, bWt, stats, nullptr);
    lse_fix<<<dim3(32), blk, 0, stream>>>(stats, out);
    gemm_loss<false><<<g2, blk, 0, stream>>>(bXs, bWs, bXt, bWt, stats, out);
  } else {
    // minimal-ws fallback: everything on the fly (needs only 32 KB)
    gemm_pass1<true, false><<<g1, blk, 0, stream>>>(Xs, Xt, Ws, Wt, stats, nullptr);
    lse_fix<<<dim3(32), blk, 0, stream>>>(stats, out);
    gemm_loss<true><<<g2, blk, 0, stream>>>(Xs, Ws, Xt, Wt, stats, out);
  }
  (void)in_sizes; (void)n_in; (void)out_size;
}